// Round 7
// baseline (365.587 us; speedup 1.0000x reference)
//
#include <hip/hip_runtime.h>
#include <math.h>

#define NN 30000
#define NE 480000
#define DH 256
#define NH (NN * DH)
#define MPAD 30080   // 235 * 128
#define CAP 64       // slot capacity; deg ~ Poisson(16), P(>63) ~ 1e-55

typedef _Float16 f16x4 __attribute__((ext_vector_type(4)));
typedef _Float16 f16x8 __attribute__((ext_vector_type(8)));
typedef float f32x4 __attribute__((ext_vector_type(4)));

static __device__ __forceinline__ float sigmoidf_(float x) {
    return 1.0f / (1.0f + __expf(-x));
}

// async global->LDS, 16B per lane. LDS ptr must be wave-uniform (HW adds lane*16).
static __device__ __forceinline__ void gload16(const _Float16* g, _Float16* l) {
    __builtin_amdgcn_global_load_lds(
        (const __attribute__((address_space(1))) void*)g,
        (__attribute__((address_space(3))) void*)l, 16, 0, 0);
}

// ---------------- graph prep ----------------

__global__ void deg_kernel(const int* __restrict__ src, const float* __restrict__ w,
                           float* __restrict__ deg) {
    int e = blockIdx.x * blockDim.x + threadIdx.x;
    if (e < NE) atomicAdd(&deg[src[e]], w[e]);
}

__global__ void dinv_kernel(float* __restrict__ deg) {
    int v = blockIdx.x * blockDim.x + threadIdx.x;
    if (v < NN) {
        float d = deg[v];
        deg[v] = (d > 0.0f) ? rsqrtf(fmaxf(d, 1e-12f)) : 0.0f;
    }
}

// One pass: out-list (snf, 4B) keyed by src; in-list ({src|dnf<<15, norm}, 8B) keyed by dst.
__global__ void scatter2(const int* __restrict__ src, const int* __restrict__ dst,
                         const int* __restrict__ snf, const int* __restrict__ dnf,
                         const float* __restrict__ w, const float* __restrict__ dinv,
                         int* __restrict__ cntS, int* __restrict__ cntD,
                         int* __restrict__ slotS, int2* __restrict__ slotD) {
    int e = blockIdx.x * blockDim.x + threadIdx.x;
    if (e >= NE) return;
    int s = src[e], d = dst[e];
    int pS = atomicAdd(&cntS[s], 1);
    if (pS < CAP) slotS[s * CAP + pS] = snf[e];
    float nrm = -dinv[s] * w[e] * dinv[d];
    int pD = atomicAdd(&cntD[d], 1);
    if (pD < CAP) slotD[d * CAP + pD] = make_int2(s | (dnf[e] << 15), __float_as_int(nrm));
}

// ---------------- fp16 conversion (x and h in one launch) ----------------

__global__ void conv2_f16(const float* __restrict__ a, _Float16* __restrict__ oa,
                          const float* __restrict__ b, _Float16* __restrict__ ob,
                          int n8each) {
    int i = blockIdx.x * blockDim.x + threadIdx.x;
    const float* in; _Float16* out; int idx;
    if (i < n8each) { in = a; out = oa; idx = i; }
    else if (i < 2 * n8each) { in = b; out = ob; idx = i - n8each; }
    else return;
    const float4 p = *reinterpret_cast<const float4*>(&in[(size_t)idx * 8]);
    const float4 q = *reinterpret_cast<const float4*>(&in[(size_t)idx * 8 + 4]);
    f16x8 v;
    v[0] = (_Float16)p.x; v[1] = (_Float16)p.y; v[2] = (_Float16)p.z; v[3] = (_Float16)p.w;
    v[4] = (_Float16)q.x; v[5] = (_Float16)q.y; v[6] = (_Float16)q.z; v[7] = (_Float16)q.w;
    *reinterpret_cast<f16x8*>(&out[(size_t)idx * 8]) = v;
}

// ---------------- fused gather, 8-batched for MLP ----------------
// One wave per node v (64 lanes x 4 features):
//   A16[v][0:256]   = x[v] + sum_out x[snf] + sum_in x[dnf]
//   A16[v][256:512] = h[v]
//   A16[v][512:768] = sum_in norm * h[src]
__global__ __launch_bounds__(256) void fused_gather(const _Float16* __restrict__ x16,
                                                    const _Float16* __restrict__ h16,
                                                    const int* __restrict__ cntS,
                                                    const int* __restrict__ cntD,
                                                    const int4* __restrict__ slotS4,
                                                    const int4* __restrict__ slotD4,
                                                    _Float16* __restrict__ A16) {
    int wid = (blockIdx.x * blockDim.x + threadIdx.x) >> 6;
    int l = threadIdx.x & 63;
    if (wid >= NN) return;
    int nS = min(cntS[wid], CAP);
    int nD = min(cntD[wid], CAP);

    f16x4 xv = *reinterpret_cast<const f16x4*>(&x16[(size_t)wid * 256 + l * 4]);
    f16x4 hrow = *reinterpret_cast<const f16x4*>(&h16[(size_t)wid * 256 + l * 4]);
    float a0 = (float)xv[0], a1 = (float)xv[1], a2 = (float)xv[2], a3 = (float)xv[3];
    float t0 = 0.f, t1 = 0.f, t2 = 0.f, t3 = 0.f;

    // ---- out-edges: 8 ids per iteration (2 x int4) ----
    const int4* pS = &slotS4[(size_t)wid * (CAP / 4)];
    for (int j = 0; j < nS; j += 8) {
        int4 e0 = pS[j >> 2];
        int4 e1 = pS[(j >> 2) + 1];   // within CAP allocation; values guarded below
        int ids[8] = {e0.x, e0.y, e0.z, e0.w, e1.x, e1.y, e1.z, e1.w};
        f16x4 vs[8];
        #pragma unroll
        for (int u = 0; u < 8; ++u)
            if (j + u < nS)
                vs[u] = *reinterpret_cast<const f16x4*>(&x16[(size_t)ids[u] * 256 + l * 4]);
        #pragma unroll
        for (int u = 0; u < 8; ++u)
            if (j + u < nS) {
                a0 += (float)vs[u][0]; a1 += (float)vs[u][1];
                a2 += (float)vs[u][2]; a3 += (float)vs[u][3];
            }
    }

    // ---- in-edges: 8 packed entries per iteration (4 x int4, 16 gathers in flight) ----
    const int4* pD = &slotD4[(size_t)wid * (CAP / 2)];
    for (int j = 0; j < nD; j += 8) {
        int4 q[4];
        #pragma unroll
        for (int u = 0; u < 4; ++u) q[u] = pD[(j >> 1) + u];
        f16x4 xs[8], hs[8];
        float nf[8];
        #pragma unroll
        for (int u = 0; u < 8; ++u) {
            int pk = (u & 1) ? q[u >> 1].z : q[u >> 1].x;
            nf[u] = __int_as_float((u & 1) ? q[u >> 1].w : q[u >> 1].y);
            if (j + u < nD) {
                xs[u] = *reinterpret_cast<const f16x4*>(&x16[(size_t)(pk >> 15) * 256 + l * 4]);
                hs[u] = *reinterpret_cast<const f16x4*>(&h16[(size_t)(pk & 0x7fff) * 256 + l * 4]);
            }
        }
        #pragma unroll
        for (int u = 0; u < 8; ++u)
            if (j + u < nD) {
                a0 += (float)xs[u][0]; a1 += (float)xs[u][1];
                a2 += (float)xs[u][2]; a3 += (float)xs[u][3];
                t0 += nf[u] * (float)hs[u][0]; t1 += nf[u] * (float)hs[u][1];
                t2 += nf[u] * (float)hs[u][2]; t3 += nf[u] * (float)hs[u][3];
            }
    }

    f16x4 oX, oT;
    oX[0] = (_Float16)a0; oX[1] = (_Float16)a1; oX[2] = (_Float16)a2; oX[3] = (_Float16)a3;
    oT[0] = (_Float16)t0; oT[1] = (_Float16)t1; oT[2] = (_Float16)t2; oT[3] = (_Float16)t3;
    size_t rb = (size_t)wid * 768;
    *reinterpret_cast<f16x4*>(&A16[rb + l * 4]) = oX;
    *reinterpret_cast<f16x4*>(&A16[rb + 256 + l * 4]) = hrow;
    *reinterpret_cast<f16x4*>(&A16[rb + 512 + l * 4]) = oT;
}

// ---------------- weight packing (transposed, fp16) ----------------

__global__ void wcatT_kernel(const float* __restrict__ W_i, const float* __restrict__ W_f,
                             const float* __restrict__ W_g, const float* __restrict__ W_o,
                             const float* __restrict__ Wc_i, const float* __restrict__ Wc_f,
                             const float* __restrict__ Wc_g, const float* __restrict__ Wc_o,
                             _Float16* __restrict__ WcatT) {
    int idx = blockIdx.x * blockDim.x + threadIdx.x;
    if (idx >= 768 * 1024) return;
    int k = idx >> 10, n = idx & 1023;   // n fastest -> coalesced reads
    int seg = k >> 8, kk = k & 255, gate = n >> 8, nn = n & 255;
    const float* p;
    if (seg == 0) {
        p = (gate == 0) ? W_i : (gate == 1) ? W_f : (gate == 2) ? W_g : W_o;
    } else {
        const float* base = (gate == 0) ? Wc_i : (gate == 1) ? Wc_f : (gate == 2) ? Wc_g : Wc_o;
        p = base + (seg - 1) * 65536;
    }
    WcatT[(size_t)n * 768 + k] = (_Float16)p[kk * 256 + nn];
}

__global__ void wlinT_kernel(const float* __restrict__ W_lin, _Float16* __restrict__ WlinT) {
    int idx = blockIdx.x * blockDim.x + threadIdx.x;
    if (idx >= 256 * 256) return;
    int k = idx >> 8, n = idx & 255;
    WlinT[(size_t)n * 256 + k] = (_Float16)W_lin[k * 256 + n];
}

// ---------------- fp16 MFMA GEMM (128x128 tile, BK=64, both-sides XOR swizzle) ----------------

template <int K, int N, bool HALF_OUT>
__global__ __launch_bounds__(256) void gemm16(const _Float16* __restrict__ A,
                                              const _Float16* __restrict__ B,
                                              const float* __restrict__ bias,
                                              _Float16* __restrict__ outH,
                                              float* __restrict__ outF) {
    __shared__ _Float16 As[128 * 64];
    __shared__ _Float16 Bs[128 * 64];
    int tid = threadIdx.x;
    int w = tid >> 6, l = tid & 63;
    int wy = w >> 1, wx = w & 1;
    int bm = blockIdx.x * 128, bn = blockIdx.y * 128;

    f32x4 acc[4][4];
    #pragma unroll
    for (int m = 0; m < 4; ++m)
        #pragma unroll
        for (int n = 0; n < 4; ++n)
            acc[m][n] = (f32x4){0.f, 0.f, 0.f, 0.f};

    int rowi = tid >> 3;                      // 0..31
    int g = (tid & 7) ^ (rowi & 7);           // pre-swizzled source chunk
    const _Float16* gA0 = A + (size_t)(bm + rowi) * K + g * 8;
    const _Float16* gB0 = B + (size_t)(bn + rowi) * K + g * 8;

    for (int kt = 0; kt < K; kt += 64) {
        #pragma unroll
        for (int i = 0; i < 4; ++i) {
            gload16(gA0 + kt + (size_t)i * 32 * K, &As[i * 2048 + w * 512]);
            gload16(gB0 + kt + (size_t)i * 32 * K, &Bs[i * 2048 + w * 512]);
        }
        __syncthreads();

        f16x8 af[4][2], bf[4][2];
        #pragma unroll
        for (int m = 0; m < 4; ++m) {
            int row = wy * 64 + m * 16 + (l & 15);
            #pragma unroll
            for (int ks = 0; ks < 2; ++ks) {
                int ch = (ks * 4 + (l >> 4)) ^ (l & 7);
                af[m][ks] = *reinterpret_cast<const f16x8*>(&As[row * 64 + ch * 8]);
            }
        }
        #pragma unroll
        for (int n = 0; n < 4; ++n) {
            int row = wx * 64 + n * 16 + (l & 15);
            #pragma unroll
            for (int ks = 0; ks < 2; ++ks) {
                int ch = (ks * 4 + (l >> 4)) ^ (l & 7);
                bf[n][ks] = *reinterpret_cast<const f16x8*>(&Bs[row * 64 + ch * 8]);
            }
        }
        #pragma unroll
        for (int ks = 0; ks < 2; ++ks)
            #pragma unroll
            for (int m = 0; m < 4; ++m)
                #pragma unroll
                for (int n = 0; n < 4; ++n)
                    acc[m][n] = __builtin_amdgcn_mfma_f32_16x16x32_f16(
                        af[m][ks], bf[n][ks], acc[m][n], 0, 0, 0);
        __syncthreads();
    }

    #pragma unroll
    for (int m = 0; m < 4; ++m) {
        #pragma unroll
        for (int n = 0; n < 4; ++n) {
            int col = bn + wx * 64 + n * 16 + (l & 15);
            #pragma unroll
            for (int j = 0; j < 4; ++j) {
                int row = bm + wy * 64 + m * 16 + (l >> 4) * 4 + j;
                if (row < NN) {
                    if constexpr (HALF_OUT)
                        outH[(size_t)row * N + col] = (_Float16)acc[m][n][j];
                    else
                        outF[(size_t)row * N + col] = acc[m][n][j] + bias[col];
                }
            }
        }
    }
}

// ---------------- gates ----------------

__global__ void gate_kernel(const _Float16* __restrict__ pre, const float* __restrict__ c,
                            const float* __restrict__ bc_i, const float* __restrict__ bc_f,
                            const float* __restrict__ bc_g, const float* __restrict__ bc_o,
                            const float* __restrict__ b_i, const float* __restrict__ b_f,
                            const float* __restrict__ b_g, const float* __restrict__ b_o,
                            const float* __restrict__ w_ci, const float* __restrict__ w_cf,
                            const float* __restrict__ w_co,
                            float* __restrict__ h0p, float* __restrict__ cnp,
                            _Float16* __restrict__ relu16) {
    int idx = blockIdx.x * blockDim.x + threadIdx.x;
    if (idx >= NN * 64) return;
    int row = idx >> 6;
    int n4 = (idx & 63) << 2;
    size_t pb = (size_t)row * 1024;
    f16x4 pi = *reinterpret_cast<const f16x4*>(&pre[pb + n4]);
    f16x4 pf = *reinterpret_cast<const f16x4*>(&pre[pb + 256 + n4]);
    f16x4 pg = *reinterpret_cast<const f16x4*>(&pre[pb + 512 + n4]);
    f16x4 po = *reinterpret_cast<const f16x4*>(&pre[pb + 768 + n4]);
    float4 cv = *reinterpret_cast<const float4*>(&c[(size_t)row * 256 + n4]);
    float4 vbci = *reinterpret_cast<const float4*>(&bc_i[n4]);
    float4 vbcf = *reinterpret_cast<const float4*>(&bc_f[n4]);
    float4 vbcg = *reinterpret_cast<const float4*>(&bc_g[n4]);
    float4 vbco = *reinterpret_cast<const float4*>(&bc_o[n4]);
    float4 vbi  = *reinterpret_cast<const float4*>(&b_i[n4]);
    float4 vbf  = *reinterpret_cast<const float4*>(&b_f[n4]);
    float4 vbg  = *reinterpret_cast<const float4*>(&b_g[n4]);
    float4 vbo  = *reinterpret_cast<const float4*>(&b_o[n4]);
    float4 vwci = *reinterpret_cast<const float4*>(&w_ci[n4]);
    float4 vwcf = *reinterpret_cast<const float4*>(&w_cf[n4]);
    float4 vwco = *reinterpret_cast<const float4*>(&w_co[n4]);
    const float* CV = (const float*)&cv;
    const float* BCI = (const float*)&vbci; const float* BCF = (const float*)&vbcf;
    const float* BCG = (const float*)&vbcg; const float* BCO = (const float*)&vbco;
    const float* BI = (const float*)&vbi;   const float* BF = (const float*)&vbf;
    const float* BG = (const float*)&vbg;   const float* BO = (const float*)&vbo;
    const float* WCI = (const float*)&vwci; const float* WCF = (const float*)&vwcf;
    const float* WCO = (const float*)&vwco;
    float4 cn4, h04;
    float* CN = (float*)&cn4; float* H0 = (float*)&h04;
    f16x4 rl;
    #pragma unroll
    for (int j = 0; j < 4; ++j) {
        float iv = sigmoidf_((float)pi[j] + BCI[j] + BI[j] + WCI[j] * CV[j]);
        float fv = sigmoidf_((float)pf[j] + BCF[j] + BF[j] + WCF[j] * CV[j]);
        float gv = tanhf((float)pg[j] + BCG[j] + BG[j]);
        float cn = fv * CV[j] + iv * gv;
        float ov = sigmoidf_((float)po[j] + BCO[j] + BO[j] + WCO[j] * cn);
        CN[j] = cn;
        float h0 = ov * tanhf(cn);
        H0[j] = h0;
        rl[j] = (_Float16)fmaxf(h0, 0.f);
    }
    *reinterpret_cast<float4*>(&cnp[(size_t)row * 256 + n4]) = cn4;
    *reinterpret_cast<float4*>(&h0p[(size_t)row * 256 + n4]) = h04;
    *reinterpret_cast<f16x4*>(&relu16[(size_t)row * 256 + n4]) = rl;
}

// ---------------- launch ----------------

extern "C" void kernel_launch(void* const* d_in, const int* in_sizes, int n_in,
                              void* d_out, int out_size, void* d_ws, size_t ws_size,
                              hipStream_t stream) {
    const float* x   = (const float*)d_in[0];
    const int*   ei  = (const int*)d_in[1];
    const float* ew  = (const float*)d_in[2];
    const float* h   = (const float*)d_in[3];
    const float* c   = (const float*)d_in[4];
    const int*   snf = (const int*)d_in[5];
    const int*   dnf = (const int*)d_in[6];
    const float* W_i = (const float*)d_in[7];
    const float* W_f = (const float*)d_in[8];
    const float* W_g = (const float*)d_in[9];
    const float* W_o = (const float*)d_in[10];
    const float* Wc_i = (const float*)d_in[11];
    const float* Wc_f = (const float*)d_in[12];
    const float* Wc_g = (const float*)d_in[13];
    const float* Wc_o = (const float*)d_in[14];
    const float* bc_i = (const float*)d_in[15];
    const float* bc_f = (const float*)d_in[16];
    const float* bc_g = (const float*)d_in[17];
    const float* bc_o = (const float*)d_in[18];
    const float* b_i  = (const float*)d_in[19];
    const float* b_f  = (const float*)d_in[20];
    const float* b_g  = (const float*)d_in[21];
    const float* b_o  = (const float*)d_in[22];
    const float* b_lin = (const float*)d_in[23];
    const float* w_ci = (const float*)d_in[24];
    const float* w_cf = (const float*)d_in[25];
    const float* w_co = (const float*)d_in[26];
    const float* W_lin = (const float*)d_in[27];

    const int* src = ei;
    const int* dst = ei + NE;

    float* out = (float*)d_out;
    float* houtp = out;            // h_out
    float* h0p   = out + NH;       // h0
    float* cnp   = out + 2 * NH;   // c_new

    // ---- workspace layout (124,837,888 B total; ws >= 126,156,800 proven) ----
    char* ws = (char*)d_ws;
    _Float16* pre16 = (_Float16*)ws;                 // 61,440,000 B
    // aliased inside pre16 (all dead before gemm_pre writes pre16):
    int* cntS = (int*)ws;                            // 131,072
    int* cntD = (int*)(ws + 131072);                 // 131,072
    int* slotS = (int*)(ws + 262144);                // 30000*64*4 = 7,680,000
    int2* slotD = (int2*)(ws + 7942144);             // 30000*64*8 = 15,360,000
    _Float16* h16 = (_Float16*)(ws + 23302144);      // 15,360,000 -> ends 38,662,144 < 61.44M

    _Float16* A16 = (_Float16*)(ws + 61440000);      // [30080][768] = 46,202,880 B
    _Float16* A16lin = A16;                          // alias: [30080][256], after gemm_pre
    _Float16* WcatT = (_Float16*)(ws + 107642880);   // 1,572,864 B
    _Float16* WlinT = (_Float16*)(ws + 109215744);   // 131,072 B
    float* deg = (float*)(ws + 109346816);           // 131,072 B
    _Float16* x16 = (_Float16*)(ws + 109477888);     // 15,360,000 B -> 124,837,888

    // 1. init counters
    hipMemsetAsync(deg, 0, 131072, stream);
    hipMemsetAsync(cntS, 0, 262144, stream);   // cntS + cntD contiguous

    // 2. degree + dinv
    deg_kernel<<<(NE + 255) / 256, 256, 0, stream>>>(src, ew, deg);
    dinv_kernel<<<(NN + 255) / 256, 256, 0, stream>>>(deg);

    // 3. fp16 conversions (x and h, one launch)
    conv2_f16<<<7500, 256, 0, stream>>>(x, x16, h, h16, NN * 32);

    // 4. slot-bucket build
    scatter2<<<(NE + 255) / 256, 256, 0, stream>>>(src, dst, snf, dnf, ew, deg,
                                                   cntS, cntD, slotS, slotD);

    // 5. fused gather -> all three A16 segments
    fused_gather<<<7500, 256, 0, stream>>>(x16, h16, cntS, cntD,
                                           (const int4*)slotS, (const int4*)slotD, A16);
    hipMemsetAsync((char*)A16 + (size_t)NN * 768 * 2, 0, (size_t)(MPAD - NN) * 768 * 2, stream);

    // 6. pack weights
    wcatT_kernel<<<3072, 256, 0, stream>>>(W_i, W_f, W_g, W_o, Wc_i, Wc_f, Wc_g, Wc_o, WcatT);
    wlinT_kernel<<<256, 256, 0, stream>>>(W_lin, WlinT);

    // 7. big GEMM: pre16 = A16 @ WcatT^T
    dim3 g1(MPAD / 128, 1024 / 128);
    gemm16<768, 1024, true><<<g1, 256, 0, stream>>>(A16, WcatT, nullptr, pre16, nullptr);

    // 8. gates (writes h0, c_new outputs + relu(h0) fp16 over A16 base)
    gate_kernel<<<7500, 256, 0, stream>>>(pre16, c, bc_i, bc_f, bc_g, bc_o,
                                          b_i, b_f, b_g, b_o, w_ci, w_cf, w_co,
                                          h0p, cnp, A16lin);
    hipMemsetAsync((char*)A16lin + (size_t)NN * 256 * 2, 0, (size_t)(MPAD - NN) * 256 * 2, stream);

    // 9. h_out = relu(h0) @ W_lin + b_lin
    dim3 g2(MPAD / 128, 256 / 128);
    gemm16<256, 256, false><<<g2, 256, 0, stream>>>(A16lin, WlinT, b_lin, nullptr, houtp);
}

// Round 8
// 337.021 us; speedup vs baseline: 1.0848x; 1.0848x over previous
//
#include <hip/hip_runtime.h>
#include <math.h>

#define NN 30000
#define NE 480000
#define DH 256
#define NH (NN * DH)
#define MPAD 30080   // 235 * 128
#define CAP 64       // slot capacity; deg ~ Poisson(16), P(>63) ~ 1e-55

typedef _Float16 f16x4 __attribute__((ext_vector_type(4)));
typedef _Float16 f16x8 __attribute__((ext_vector_type(8)));
typedef float f32x4 __attribute__((ext_vector_type(4)));

static __device__ __forceinline__ float sigmoidf_(float x) {
    return 1.0f / (1.0f + __expf(-x));
}

// async global->LDS, 16B per lane. LDS ptr must be wave-uniform (HW adds lane*16).
static __device__ __forceinline__ void gload16(const _Float16* g, _Float16* l) {
    __builtin_amdgcn_global_load_lds(
        (const __attribute__((address_space(1))) void*)g,
        (__attribute__((address_space(3))) void*)l, 16, 0, 0);
}

// ---------------- prep0: deg atomics (blocks 0..1874) + x/h fp16 conv (rest) ----------------

__global__ void prep0(const int* __restrict__ src, const float* __restrict__ ew,
                      float* __restrict__ deg,
                      const float* __restrict__ x, _Float16* __restrict__ x16,
                      const float* __restrict__ h, _Float16* __restrict__ h16) {
    int b = blockIdx.x;
    if (b < 1875) {
        int e = b * 256 + threadIdx.x;
        if (e < NE) atomicAdd(&deg[src[e]], ew[e]);
        return;
    }
    int i = (b - 1875) * 256 + threadIdx.x;   // [0, 2*NN*32)
    const int n8 = NN * 32;
    const float* in; _Float16* out; int idx;
    if (i < n8) { in = x; out = x16; idx = i; }
    else if (i < 2 * n8) { in = h; out = h16; idx = i - n8; }
    else return;
    const float4 p = *reinterpret_cast<const float4*>(&in[(size_t)idx * 8]);
    const float4 q = *reinterpret_cast<const float4*>(&in[(size_t)idx * 8 + 4]);
    f16x8 v;
    v[0] = (_Float16)p.x; v[1] = (_Float16)p.y; v[2] = (_Float16)p.z; v[3] = (_Float16)p.w;
    v[4] = (_Float16)q.x; v[5] = (_Float16)q.y; v[6] = (_Float16)q.z; v[7] = (_Float16)q.w;
    *reinterpret_cast<f16x8*>(&out[(size_t)idx * 8]) = v;
}

__global__ void dinv_kernel(float* __restrict__ deg) {
    int v = blockIdx.x * blockDim.x + threadIdx.x;
    if (v < NN) {
        float d = deg[v];
        deg[v] = (d > 0.0f) ? rsqrtf(fmaxf(d, 1e-12f)) : 0.0f;
    }
}

// One pass: out-list (snf, 4B) keyed by src; in-list ({src|dnf<<15, norm}, 8B) keyed by dst.
__global__ void scatter2(const int* __restrict__ src, const int* __restrict__ dst,
                         const int* __restrict__ snf, const int* __restrict__ dnf,
                         const float* __restrict__ w, const float* __restrict__ dinv,
                         int* __restrict__ cntS, int* __restrict__ cntD,
                         int* __restrict__ slotS, int2* __restrict__ slotD) {
    int e = blockIdx.x * blockDim.x + threadIdx.x;
    if (e >= NE) return;
    int s = src[e], d = dst[e];
    int pS = atomicAdd(&cntS[s], 1);
    if (pS < CAP) slotS[s * CAP + pS] = snf[e];
    float nrm = -dinv[s] * w[e] * dinv[d];
    int pD = atomicAdd(&cntD[d], 1);
    if (pD < CAP) slotD[d * CAP + pD] = make_int2(s | (dnf[e] << 15), __float_as_int(nrm));
}

// ---------------- fused gather, 4-batched (Round-6 proven) + pad-row zeroing ----------------
// One wave per node v (64 lanes x 4 features):
//   A16[v][0:256]   = x[v] + sum_out x[snf] + sum_in x[dnf]
//   A16[v][256:512] = h[v]
//   A16[v][512:768] = sum_in norm * h[src]
__global__ __launch_bounds__(256) void fused_gather(const _Float16* __restrict__ x16,
                                                    const _Float16* __restrict__ h16,
                                                    const int* __restrict__ cntS,
                                                    const int* __restrict__ cntD,
                                                    const int4* __restrict__ slotS4,
                                                    const int4* __restrict__ slotD4,
                                                    _Float16* __restrict__ A16) {
    int wid = (blockIdx.x * blockDim.x + threadIdx.x) >> 6;
    int l = threadIdx.x & 63;
    if (wid >= MPAD) return;
    size_t rb = (size_t)wid * 768;
    if (wid >= NN) {   // pad rows: zero all three segments
        f16x4 z = {};
        *reinterpret_cast<f16x4*>(&A16[rb + l * 4]) = z;
        *reinterpret_cast<f16x4*>(&A16[rb + 256 + l * 4]) = z;
        *reinterpret_cast<f16x4*>(&A16[rb + 512 + l * 4]) = z;
        return;
    }
    int nS = min(cntS[wid], CAP);
    int nD = min(cntD[wid], CAP);

    f16x4 xv = *reinterpret_cast<const f16x4*>(&x16[(size_t)wid * 256 + l * 4]);
    f16x4 hrow = *reinterpret_cast<const f16x4*>(&h16[(size_t)wid * 256 + l * 4]);
    float a0 = (float)xv[0], a1 = (float)xv[1], a2 = (float)xv[2], a3 = (float)xv[3];
    float t0 = 0.f, t1 = 0.f, t2 = 0.f, t3 = 0.f;

    // ---- out-edges: 4 ids per int4 ----
    const int4* pS = &slotS4[(size_t)wid * (CAP / 4)];
    for (int j = 0; j < nS; j += 4) {
        int4 e = pS[j >> 2];
        f16x4 v0, v1, v2, v3;
        v0 = *reinterpret_cast<const f16x4*>(&x16[(size_t)e.x * 256 + l * 4]);
        if (j + 1 < nS) v1 = *reinterpret_cast<const f16x4*>(&x16[(size_t)e.y * 256 + l * 4]);
        if (j + 2 < nS) v2 = *reinterpret_cast<const f16x4*>(&x16[(size_t)e.z * 256 + l * 4]);
        if (j + 3 < nS) v3 = *reinterpret_cast<const f16x4*>(&x16[(size_t)e.w * 256 + l * 4]);
        a0 += (float)v0[0]; a1 += (float)v0[1]; a2 += (float)v0[2]; a3 += (float)v0[3];
        if (j + 1 < nS) { a0 += (float)v1[0]; a1 += (float)v1[1]; a2 += (float)v1[2]; a3 += (float)v1[3]; }
        if (j + 2 < nS) { a0 += (float)v2[0]; a1 += (float)v2[1]; a2 += (float)v2[2]; a3 += (float)v2[3]; }
        if (j + 3 < nS) { a0 += (float)v3[0]; a1 += (float)v3[1]; a2 += (float)v3[2]; a3 += (float)v3[3]; }
    }

    // ---- in-edges: 2 packed entries per int4, batch 4 entries (2 x int4) ----
    const int4* pD = &slotD4[(size_t)wid * (CAP / 2)];
    for (int j = 0; j < nD; j += 4) {
        int4 ea = pD[(j >> 2) * 2];
        int4 eb = pD[(j >> 2) * 2 + 1];
        int p0 = ea.x, p1 = ea.z, p2 = eb.x, p3 = eb.z;
        float n0 = __int_as_float(ea.y), n1f = __int_as_float(ea.w);
        float n2f = __int_as_float(eb.y), n3f = __int_as_float(eb.w);
        f16x4 x0, x1, x2, x3, g0, g1, g2, g3;
        x0 = *reinterpret_cast<const f16x4*>(&x16[(size_t)(p0 >> 15) * 256 + l * 4]);
        g0 = *reinterpret_cast<const f16x4*>(&h16[(size_t)(p0 & 0x7fff) * 256 + l * 4]);
        if (j + 1 < nD) {
            x1 = *reinterpret_cast<const f16x4*>(&x16[(size_t)(p1 >> 15) * 256 + l * 4]);
            g1 = *reinterpret_cast<const f16x4*>(&h16[(size_t)(p1 & 0x7fff) * 256 + l * 4]);
        }
        if (j + 2 < nD) {
            x2 = *reinterpret_cast<const f16x4*>(&x16[(size_t)(p2 >> 15) * 256 + l * 4]);
            g2 = *reinterpret_cast<const f16x4*>(&h16[(size_t)(p2 & 0x7fff) * 256 + l * 4]);
        }
        if (j + 3 < nD) {
            x3 = *reinterpret_cast<const f16x4*>(&x16[(size_t)(p3 >> 15) * 256 + l * 4]);
            g3 = *reinterpret_cast<const f16x4*>(&h16[(size_t)(p3 & 0x7fff) * 256 + l * 4]);
        }
        a0 += (float)x0[0]; a1 += (float)x0[1]; a2 += (float)x0[2]; a3 += (float)x0[3];
        t0 += n0 * (float)g0[0]; t1 += n0 * (float)g0[1];
        t2 += n0 * (float)g0[2]; t3 += n0 * (float)g0[3];
        if (j + 1 < nD) {
            a0 += (float)x1[0]; a1 += (float)x1[1]; a2 += (float)x1[2]; a3 += (float)x1[3];
            t0 += n1f * (float)g1[0]; t1 += n1f * (float)g1[1];
            t2 += n1f * (float)g1[2]; t3 += n1f * (float)g1[3];
        }
        if (j + 2 < nD) {
            a0 += (float)x2[0]; a1 += (float)x2[1]; a2 += (float)x2[2]; a3 += (float)x2[3];
            t0 += n2f * (float)g2[0]; t1 += n2f * (float)g2[1];
            t2 += n2f * (float)g2[2]; t3 += n2f * (float)g2[3];
        }
        if (j + 3 < nD) {
            a0 += (float)x3[0]; a1 += (float)x3[1]; a2 += (float)x3[2]; a3 += (float)x3[3];
            t0 += n3f * (float)g3[0]; t1 += n3f * (float)g3[1];
            t2 += n3f * (float)g3[2]; t3 += n3f * (float)g3[3];
        }
    }

    f16x4 oX, oT;
    oX[0] = (_Float16)a0; oX[1] = (_Float16)a1; oX[2] = (_Float16)a2; oX[3] = (_Float16)a3;
    oT[0] = (_Float16)t0; oT[1] = (_Float16)t1; oT[2] = (_Float16)t2; oT[3] = (_Float16)t3;
    *reinterpret_cast<f16x4*>(&A16[rb + l * 4]) = oX;
    *reinterpret_cast<f16x4*>(&A16[rb + 256 + l * 4]) = hrow;
    *reinterpret_cast<f16x4*>(&A16[rb + 512 + l * 4]) = oT;
}

// ---------------- weight packing: Wcat^T and Wlin^T in one launch ----------------

__global__ void wpack_kernel(const float* __restrict__ W_i, const float* __restrict__ W_f,
                             const float* __restrict__ W_g, const float* __restrict__ W_o,
                             const float* __restrict__ Wc_i, const float* __restrict__ Wc_f,
                             const float* __restrict__ Wc_g, const float* __restrict__ Wc_o,
                             const float* __restrict__ W_lin,
                             _Float16* __restrict__ WcatT, _Float16* __restrict__ WlinT) {
    int idx = blockIdx.x * blockDim.x + threadIdx.x;
    if (idx < 768 * 1024) {
        int k = idx >> 10, n = idx & 1023;
        int seg = k >> 8, kk = k & 255, gate = n >> 8, nn = n & 255;
        const float* p;
        if (seg == 0) {
            p = (gate == 0) ? W_i : (gate == 1) ? W_f : (gate == 2) ? W_g : W_o;
        } else {
            const float* base = (gate == 0) ? Wc_i : (gate == 1) ? Wc_f : (gate == 2) ? Wc_g : Wc_o;
            p = base + (seg - 1) * 65536;
        }
        WcatT[(size_t)n * 768 + k] = (_Float16)p[kk * 256 + nn];
    } else {
        int i2 = idx - 768 * 1024;
        if (i2 >= 256 * 256) return;
        int k = i2 >> 8, n = i2 & 255;
        WlinT[(size_t)n * 256 + k] = (_Float16)W_lin[k * 256 + n];
    }
}

// ---------------- fp16 MFMA GEMM (128x128 tile, BK=64, both-sides XOR swizzle) ----------------
// SWZ1D: 1D grid with XCD-chunked mapping — each XCD owns a contiguous m-range with n
// cycling fastest, so the A-tile is L2-hot across all 8 column panels (cross-L2 A traffic /8).

template <int K, int N, bool HALF_OUT, bool SWZ1D>
__global__ __launch_bounds__(256) void gemm16(const _Float16* __restrict__ A,
                                              const _Float16* __restrict__ B,
                                              const float* __restrict__ bias,
                                              _Float16* __restrict__ outH,
                                              float* __restrict__ outF) {
    __shared__ _Float16 As[128 * 64];
    __shared__ _Float16 Bs[128 * 64];
    int tid = threadIdx.x;
    int w = tid >> 6, l = tid & 63;
    int wy = w >> 1, wx = w & 1;
    int bm, bn;
    if constexpr (SWZ1D) {
        constexpr int NT = N / 128;
        constexpr int TOT = (MPAD / 128) * NT;   // must be divisible by 8
        constexpr int CH = TOT / 8;
        int b = blockIdx.x;
        int v = (b & 7) * CH + (b >> 3);         // bijective when TOT%8==0
        bm = (v / NT) * 128; bn = (v % NT) * 128;
    } else {
        bm = blockIdx.x * 128; bn = blockIdx.y * 128;
    }

    f32x4 acc[4][4];
    #pragma unroll
    for (int m = 0; m < 4; ++m)
        #pragma unroll
        for (int n = 0; n < 4; ++n)
            acc[m][n] = (f32x4){0.f, 0.f, 0.f, 0.f};

    int rowi = tid >> 3;                      // 0..31
    int g = (tid & 7) ^ (rowi & 7);           // pre-swizzled source chunk
    const _Float16* gA0 = A + (size_t)(bm + rowi) * K + g * 8;
    const _Float16* gB0 = B + (size_t)(bn + rowi) * K + g * 8;

    for (int kt = 0; kt < K; kt += 64) {
        #pragma unroll
        for (int i = 0; i < 4; ++i) {
            gload16(gA0 + kt + (size_t)i * 32 * K, &As[i * 2048 + w * 512]);
            gload16(gB0 + kt + (size_t)i * 32 * K, &Bs[i * 2048 + w * 512]);
        }
        __syncthreads();

        f16x8 af[4][2], bf[4][2];
        #pragma unroll
        for (int m = 0; m < 4; ++m) {
            int row = wy * 64 + m * 16 + (l & 15);
            #pragma unroll
            for (int ks = 0; ks < 2; ++ks) {
                int ch = (ks * 4 + (l >> 4)) ^ (l & 7);
                af[m][ks] = *reinterpret_cast<const f16x8*>(&As[row * 64 + ch * 8]);
            }
        }
        #pragma unroll
        for (int n = 0; n < 4; ++n) {
            int row = wx * 64 + n * 16 + (l & 15);
            #pragma unroll
            for (int ks = 0; ks < 2; ++ks) {
                int ch = (ks * 4 + (l >> 4)) ^ (l & 7);
                bf[n][ks] = *reinterpret_cast<const f16x8*>(&Bs[row * 64 + ch * 8]);
            }
        }
        #pragma unroll
        for (int ks = 0; ks < 2; ++ks)
            #pragma unroll
            for (int m = 0; m < 4; ++m)
                #pragma unroll
                for (int n = 0; n < 4; ++n)
                    acc[m][n] = __builtin_amdgcn_mfma_f32_16x16x32_f16(
                        af[m][ks], bf[n][ks], acc[m][n], 0, 0, 0);
        __syncthreads();
    }

    #pragma unroll
    for (int m = 0; m < 4; ++m) {
        #pragma unroll
        for (int n = 0; n < 4; ++n) {
            int col = bn + wx * 64 + n * 16 + (l & 15);
            #pragma unroll
            for (int j = 0; j < 4; ++j) {
                int row = bm + wy * 64 + m * 16 + (l >> 4) * 4 + j;
                if (row < NN) {
                    if constexpr (HALF_OUT)
                        outH[(size_t)row * N + col] = (_Float16)acc[m][n][j];
                    else
                        outF[(size_t)row * N + col] = acc[m][n][j] + bias[col];
                }
            }
        }
    }
}

// ---------------- gates (+ pad-row zeroing of relu16) ----------------

__global__ void gate_kernel(const _Float16* __restrict__ pre, const float* __restrict__ c,
                            const float* __restrict__ bc_i, const float* __restrict__ bc_f,
                            const float* __restrict__ bc_g, const float* __restrict__ bc_o,
                            const float* __restrict__ b_i, const float* __restrict__ b_f,
                            const float* __restrict__ b_g, const float* __restrict__ b_o,
                            const float* __restrict__ w_ci, const float* __restrict__ w_cf,
                            const float* __restrict__ w_co,
                            float* __restrict__ h0p, float* __restrict__ cnp,
                            _Float16* __restrict__ relu16) {
    int idx = blockIdx.x * blockDim.x + threadIdx.x;
    if (idx >= MPAD * 64) return;
    int row = idx >> 6;
    int n4 = (idx & 63) << 2;
    if (row >= NN) {   // pad rows: zero relu16 only
        f16x4 z = {};
        *reinterpret_cast<f16x4*>(&relu16[(size_t)row * 256 + n4]) = z;
        return;
    }
    size_t pb = (size_t)row * 1024;
    f16x4 pi = *reinterpret_cast<const f16x4*>(&pre[pb + n4]);
    f16x4 pf = *reinterpret_cast<const f16x4*>(&pre[pb + 256 + n4]);
    f16x4 pg = *reinterpret_cast<const f16x4*>(&pre[pb + 512 + n4]);
    f16x4 po = *reinterpret_cast<const f16x4*>(&pre[pb + 768 + n4]);
    float4 cv = *reinterpret_cast<const float4*>(&c[(size_t)row * 256 + n4]);
    float4 vbci = *reinterpret_cast<const float4*>(&bc_i[n4]);
    float4 vbcf = *reinterpret_cast<const float4*>(&bc_f[n4]);
    float4 vbcg = *reinterpret_cast<const float4*>(&bc_g[n4]);
    float4 vbco = *reinterpret_cast<const float4*>(&bc_o[n4]);
    float4 vbi  = *reinterpret_cast<const float4*>(&b_i[n4]);
    float4 vbf  = *reinterpret_cast<const float4*>(&b_f[n4]);
    float4 vbg  = *reinterpret_cast<const float4*>(&b_g[n4]);
    float4 vbo  = *reinterpret_cast<const float4*>(&b_o[n4]);
    float4 vwci = *reinterpret_cast<const float4*>(&w_ci[n4]);
    float4 vwcf = *reinterpret_cast<const float4*>(&w_cf[n4]);
    float4 vwco = *reinterpret_cast<const float4*>(&w_co[n4]);
    const float* CV = (const float*)&cv;
    const float* BCI = (const float*)&vbci; const float* BCF = (const float*)&vbcf;
    const float* BCG = (const float*)&vbcg; const float* BCO = (const float*)&vbco;
    const float* BI = (const float*)&vbi;   const float* BF = (const float*)&vbf;
    const float* BG = (const float*)&vbg;   const float* BO = (const float*)&vbo;
    const float* WCI = (const float*)&vwci; const float* WCF = (const float*)&vwcf;
    const float* WCO = (const float*)&vwco;
    float4 cn4, h04;
    float* CN = (float*)&cn4; float* H0 = (float*)&h04;
    f16x4 rl;
    #pragma unroll
    for (int j = 0; j < 4; ++j) {
        float iv = sigmoidf_((float)pi[j] + BCI[j] + BI[j] + WCI[j] * CV[j]);
        float fv = sigmoidf_((float)pf[j] + BCF[j] + BF[j] + WCF[j] * CV[j]);
        float gv = tanhf((float)pg[j] + BCG[j] + BG[j]);
        float cn = fv * CV[j] + iv * gv;
        float ov = sigmoidf_((float)po[j] + BCO[j] + BO[j] + WCO[j] * cn);
        CN[j] = cn;
        float h0 = ov * tanhf(cn);
        H0[j] = h0;
        rl[j] = (_Float16)fmaxf(h0, 0.f);
    }
    *reinterpret_cast<float4*>(&cnp[(size_t)row * 256 + n4]) = cn4;
    *reinterpret_cast<float4*>(&h0p[(size_t)row * 256 + n4]) = h04;
    *reinterpret_cast<f16x4*>(&relu16[(size_t)row * 256 + n4]) = rl;
}

// ---------------- launch ----------------

extern "C" void kernel_launch(void* const* d_in, const int* in_sizes, int n_in,
                              void* d_out, int out_size, void* d_ws, size_t ws_size,
                              hipStream_t stream) {
    const float* x   = (const float*)d_in[0];
    const int*   ei  = (const int*)d_in[1];
    const float* ew  = (const float*)d_in[2];
    const float* h   = (const float*)d_in[3];
    const float* c   = (const float*)d_in[4];
    const int*   snf = (const int*)d_in[5];
    const int*   dnf = (const int*)d_in[6];
    const float* W_i = (const float*)d_in[7];
    const float* W_f = (const float*)d_in[8];
    const float* W_g = (const float*)d_in[9];
    const float* W_o = (const float*)d_in[10];
    const float* Wc_i = (const float*)d_in[11];
    const float* Wc_f = (const float*)d_in[12];
    const float* Wc_g = (const float*)d_in[13];
    const float* Wc_o = (const float*)d_in[14];
    const float* bc_i = (const float*)d_in[15];
    const float* bc_f = (const float*)d_in[16];
    const float* bc_g = (const float*)d_in[17];
    const float* bc_o = (const float*)d_in[18];
    const float* b_i  = (const float*)d_in[19];
    const float* b_f  = (const float*)d_in[20];
    const float* b_g  = (const float*)d_in[21];
    const float* b_o  = (const float*)d_in[22];
    const float* b_lin = (const float*)d_in[23];
    const float* w_ci = (const float*)d_in[24];
    const float* w_cf = (const float*)d_in[25];
    const float* w_co = (const float*)d_in[26];
    const float* W_lin = (const float*)d_in[27];

    const int* src = ei;
    const int* dst = ei + NE;

    float* out = (float*)d_out;
    float* houtp = out;            // h_out
    float* h0p   = out + NH;       // h0
    float* cnp   = out + 2 * NH;   // c_new

    // ---- workspace layout (124,706,816 B total; ws >= 126,156,800 proven) ----
    char* ws = (char*)d_ws;
    _Float16* pre16 = (_Float16*)ws;                 // 61,440,000 B
    // aliased inside pre16 (all dead before gemm_pre writes pre16):
    int* cntS = (int*)ws;                            // 131,072
    int* cntD = (int*)(ws + 131072);                 // 131,072
    float* deg = (float*)(ws + 262144);              // 131,072 (contiguous w/ counters)
    int* slotS = (int*)(ws + 393216);                // 30000*64*4 = 7,680,000
    int2* slotD = (int2*)(ws + 8073216);             // 30000*64*8 = 15,360,000
    _Float16* h16 = (_Float16*)(ws + 23433216);      // 15,360,000 -> ends 38,793,216 < 61.44M

    _Float16* A16 = (_Float16*)(ws + 61440000);      // [30080][768] = 46,202,880 B
    _Float16* A16lin = A16;                          // alias: [30080][256], after gemm_pre
    _Float16* WcatT = (_Float16*)(ws + 107642880);   // 1,572,864 B
    _Float16* WlinT = (_Float16*)(ws + 109215744);   // 131,072 B
    _Float16* x16 = (_Float16*)(ws + 109346816);     // 15,360,000 B -> 124,706,816

    // 1. one memset covers cntS + cntD + deg
    hipMemsetAsync(ws, 0, 393216, stream);

    // 2. deg atomics + x/h fp16 conversion (one launch)
    prep0<<<9375, 256, 0, stream>>>(src, ew, deg, x, x16, h, h16);
    dinv_kernel<<<118, 256, 0, stream>>>(deg);

    // 3. slot-bucket build
    scatter2<<<1875, 256, 0, stream>>>(src, dst, snf, dnf, ew, deg,
                                       cntS, cntD, slotS, slotD);

    // 4. fused gather -> all three A16 segments (incl. pad rows)
    fused_gather<<<7520, 256, 0, stream>>>(x16, h16, cntS, cntD,
                                           (const int4*)slotS, (const int4*)slotD, A16);

    // 5. pack weights (both, one launch)
    wpack_kernel<<<3328, 256, 0, stream>>>(W_i, W_f, W_g, W_o, Wc_i, Wc_f, Wc_g, Wc_o,
                                           W_lin, WcatT, WlinT);

    // 6. big GEMM with XCD-chunked swizzle: pre16 = A16 @ WcatT^T
    gemm16<768, 1024, true, true><<<1880, 256, 0, stream>>>(A16, WcatT, nullptr, pre16, nullptr);

    // 7. gates (writes h0, c_new + relu(h0) fp16 over A16 base, incl. pad rows)
    gate_kernel<<<7520, 256, 0, stream>>>(pre16, c, bc_i, bc_f, bc_g, bc_o,
                                          b_i, b_f, b_g, b_o, w_ci, w_cf, w_co,
                                          h0p, cnp, A16lin);

    // 8. h_out = relu(h0) @ W_lin + b_lin
    dim3 g2(MPAD / 128, 256 / 128);
    gemm16<256, 256, false, false><<<g2, 256, 0, stream>>>(A16lin, WlinT, b_lin, nullptr, houtp);
}